// Round 10
// baseline (1186.316 us; speedup 1.0000x reference)
//
#include <hip/hip_runtime.h>

typedef float f32x4 __attribute__((ext_vector_type(4)));
typedef int i32x4 __attribute__((ext_vector_type(4)));
typedef int i32x8 __attribute__((ext_vector_type(8)));

#define HDIM 4096
#define NKB 32  // 4096/128

// ---------------- K0: weight fp32 -> fp8 e4m3fn (RNE), row-major ----------------
__global__ __launch_bounds__(256) void wquant_kernel(const float* __restrict__ w,
                                                     unsigned char* __restrict__ w8,
                                                     int n4) {
  int i = blockIdx.x * 256 + threadIdx.x;
  if (i >= n4) return;
  const float4 v = ((const float4*)w)[i];
  int p = 0;
  p = __builtin_amdgcn_cvt_pk_fp8_f32(v.x, v.y, p, false);
  p = __builtin_amdgcn_cvt_pk_fp8_f32(v.z, v.w, p, true);
  ((int*)w8)[i] = p;
}

// ------------- K1/K3: (relu) + RMSNorm + group fp8 quant (row-major qa) -------------
template <int MODE>
__global__ __launch_bounds__(256) void norm_quant_kernel(
    const float* __restrict__ src, float* __restrict__ resid,
    const float* __restrict__ nw, unsigned char* __restrict__ qa,
    float* __restrict__ ascT, float* __restrict__ out) {
  const int row = blockIdx.x;
  const int tid = threadIdx.x;
  const float* srow = src + (size_t)row * HDIM;
  float4 v[4];
  float ss = 0.f;
#pragma unroll
  for (int c = 0; c < 4; ++c) {
    float4 t = ((const float4*)srow)[c * 256 + tid];
    if (MODE == 0) {
      t.x = fmaxf(t.x, 0.f); t.y = fmaxf(t.y, 0.f);
      t.z = fmaxf(t.z, 0.f); t.w = fmaxf(t.w, 0.f);
      ((float4*)(resid + (size_t)row * HDIM))[c * 256 + tid] = t;
    }
    v[c] = t;
    ss += t.x * t.x + t.y * t.y + t.z * t.z + t.w * t.w;
  }
#pragma unroll
  for (int m = 32; m >= 1; m >>= 1) ss += __shfl_xor(ss, m);
  __shared__ float red[4];
  if ((tid & 63) == 0) red[tid >> 6] = ss;
  __syncthreads();
  const float tot = red[0] + red[1] + red[2] + red[3];
  const float rstd = rsqrtf(tot * (1.f / (float)HDIM) + 1e-6f);
#pragma unroll
  for (int c = 0; c < 4; ++c) {
    float4 wv = ((const float4*)nw)[c * 256 + tid];
    float4 y;
    y.x = v[c].x * rstd * wv.x;
    y.y = v[c].y * rstd * wv.y;
    y.z = v[c].z * rstd * wv.z;
    y.w = v[c].w * rstd * wv.w;
    if (MODE == 2) {
      ((float4*)(out + (size_t)row * HDIM))[c * 256 + tid] = y;
    } else {
      float amax = fmaxf(fmaxf(fabsf(y.x), fabsf(y.y)), fmaxf(fabsf(y.z), fabsf(y.w)));
#pragma unroll
      for (int m = 16; m >= 1; m >>= 1) amax = fmaxf(amax, __shfl_xor(amax, m));
      const float scale = fmaxf(amax / 448.f, 1e-10f);
      const float qinv = __builtin_amdgcn_rcpf(scale);
      float qx = fminf(fmaxf(y.x * qinv, -448.f), 448.f);
      float qy = fminf(fmaxf(y.y * qinv, -448.f), 448.f);
      float qz = fminf(fmaxf(y.z * qinv, -448.f), 448.f);
      float qw = fminf(fmaxf(y.w * qinv, -448.f), 448.f);
      int p = 0;
      p = __builtin_amdgcn_cvt_pk_fp8_f32(qx, qy, p, false);
      p = __builtin_amdgcn_cvt_pk_fp8_f32(qz, qw, p, true);
      const int off = (c * 256 + tid) << 2;
      *(int*)(qa + (size_t)row * HDIM + off) = p;
      if ((tid & 31) == 0) ascT[(c * 8 + (tid >> 5)) * HDIM + row] = scale;
    }
  }
}

// ---------------- K2: 128x128 block-scaled fp8 GEMM via MX-rate MFMA ---------
// Occupancy-first retile of the proven R8 structure: same 16x16x128 MFMA,
// same fragment-major LDS layout and thin-phase clusters, but 128x128 tile:
//   acc/thread = 32 regs (vs 128) -> __launch_bounds__(512,4) fits
//   (live audit: acc32+aF16+bF16+svw8+addr~20+trans16 ~= 110 < 128);
//   LDS = 2 x (16K A + 16K B + 1K S) = 66K -> 2 blocks/CU, 4 waves/SIMD.
// Per-CU pipe workloads are IDENTICAL to the 256 kernel (224 b128 reads/kb,
// same MFMA cyc, ~same staging bytes) — the delta is pure latency hiding.
// Schedule: 2 thin phases/kb (4 MFMA + immediate fold each), all 5 stages
// issued at ph0, ONE vmcnt(0)+barrier per kb — the R9 drain exposure is
// covered by the co-resident second block (m97 precedent at >=2 blocks/CU).
// 8 waves = 4 wm (32 rows) x 2 wn (64 cols); per wave 2 mt x 4 nt MFMAs.
__global__ __launch_bounds__(512, 4) void gemm256_kernel(
    const unsigned char* __restrict__ qa, const float* __restrict__ ascT,
    const unsigned char* __restrict__ w8, const float* __restrict__ wsc,
    float* __restrict__ resid) {
  extern __shared__ char smem[];
  char* ldsA = smem;            // 2 x 16384
  char* ldsB = smem + 32768;    // 2 x 16384
  char* ldsS = smem + 65536;    // 2 x 1024 (512B used)

  const int tid = threadIdx.x;
  const int lane = tid & 63;
  const int wid = tid >> 6;
  const int wm = wid >> 1;   // 0..3 (32-row group)
  const int wn = wid & 1;    // 0..1 (64-col group)

  // XCD-aware bijective swizzle of the 32x32 grid (8 XCDs x 128 blocks)
  const int bflat = blockIdx.y * 32 + blockIdx.x;
  const int bswz = (bflat & 7) * 128 + (bflat >> 3);
  const int m0 = (bswz >> 5) << 7;
  const int n0 = (bswz & 31) << 7;

  const int ln15 = lane & 15;
  const int g = lane >> 4;

  // staging source offsets (row-major qa/w8): chunk CH = 8KB = 4 tiles;
  // thread t writes chunk unit t: tile (t>>7)&3, half (t>>6)&1, lane t&63.
  // Source row = tile*16 + (t&15), k = ((t>>4)&3)*32 + half*16.
  int ofs[2];
  {
    const int rowp = ((tid >> 7) & 3) * 16 + (tid & 15);
    const int kp = ((tid >> 4) & 3) * 32 + ((tid >> 6) & 1) * 16;
#pragma unroll
    for (int ch = 0; ch < 2; ++ch) ofs[ch] = (ch * 64 + rowp) * HDIM + kp;
  }
  const unsigned char* gA = qa + (size_t)m0 * HDIM;
  const unsigned char* gB = w8 + (size_t)n0 * HDIM;
  const float* sS = ascT + m0 + lane * 4;  // lanes 0..31 cover 128 rows

  const float* wsp = wsc + (n0 >> 7) * NKB;  // one 128-col scale block/tile

  const int abase = wm * 4096 + lane * 16;   // wm covers tiles wm*2, wm*2+1
  const int bbase = wn * 8192 + lane * 16;   // wn covers tiles wn*4 + nt
  const int svb = wm * 128 + g * 16;

  f32x4 acc[2][4];
#pragma unroll
  for (int i = 0; i < 2; ++i)
#pragma unroll
    for (int j = 0; j < 4; ++j) acc[i][j] = (f32x4){0.f, 0.f, 0.f, 0.f};

  i32x8 aF[2];         // [mt] 32B fragment
  i32x8 bFa[2];        // nt pair 0,1
  i32x8 bFb[2];        // nt pair 2,3
  f32x4 svw[2];        // sa*sw per mt

#define STAGE_A(CH, KB, BUF)                                                              \
  __builtin_amdgcn_global_load_lds(                                                       \
      (const __attribute__((address_space(1))) void*)(gA + ofs[CH] + (KB)*128),           \
      (__attribute__((address_space(3))) void*)(ldsA + (BUF)*16384 + (CH)*8192 + tid*16), \
      16, 0, 0)
#define STAGE_B(CH, KB, BUF)                                                              \
  __builtin_amdgcn_global_load_lds(                                                       \
      (const __attribute__((address_space(1))) void*)(gB + ofs[CH] + (KB)*128),           \
      (__attribute__((address_space(3))) void*)(ldsB + (BUF)*16384 + (CH)*8192 + tid*16), \
      16, 0, 0)
#define STAGE_S(KB, BUF)                                                                  \
  if (lane < 32)                                                                          \
  __builtin_amdgcn_global_load_lds(                                                       \
      (const __attribute__((address_space(1))) void*)(sS + (size_t)(KB)*HDIM),            \
      (__attribute__((address_space(3))) void*)(ldsS + (BUF)*1024 + lane*16), 16, 0, 0)

#define RD_A(MT)                                                                          \
  {                                                                                       \
    const char* pA_ = ldsA + cb + abase + (MT)*2048;                                      \
    i32x4 lo_ = *(const i32x4*)pA_;                                                       \
    i32x4 hi_ = *(const i32x4*)(pA_ + 1024);                                              \
    aF[MT] = __builtin_shufflevector(lo_, hi_, 0, 1, 2, 3, 4, 5, 6, 7);                   \
  }
#define RD_SVW(MT) svw[MT] = *(const f32x4*)(ldsS + cur * 1024 + svb + (MT)*64) * sw;
#define RD_B(NT, DST)                                                                     \
  {                                                                                       \
    const char* pB_ = ldsB + cb + bbase + (NT)*2048;                                      \
    i32x4 lo_ = *(const i32x4*)pB_;                                                       \
    i32x4 hi_ = *(const i32x4*)(pB_ + 1024);                                              \
    DST = __builtin_shufflevector(lo_, hi_, 0, 1, 2, 3, 4, 5, 6, 7);                      \
  }

// wave-local phase ordering: wait own ds_reads, pin program order. No barrier.
#define PH_WAIT                                                                           \
  asm volatile("s_waitcnt lgkmcnt(0)" ::: "memory");                                      \
  __builtin_amdgcn_sched_barrier(0);

#define MFMA_PH(NH, BS)                                                                   \
  __builtin_amdgcn_s_setprio(1);                                                          \
  {                                                                                       \
    const f32x4 z_ = (f32x4){0.f, 0.f, 0.f, 0.f};                                         \
    f32x4 t0 = __builtin_amdgcn_mfma_scale_f32_16x16x128_f8f6f4(                          \
        aF[0], BS[0], z_, 0, 0, 0, 127, 0, 127);                                          \
    f32x4 t1 = __builtin_amdgcn_mfma_scale_f32_16x16x128_f8f6f4(                          \
        aF[0], BS[1], z_, 0, 0, 0, 127, 0, 127);                                          \
    f32x4 t2 = __builtin_amdgcn_mfma_scale_f32_16x16x128_f8f6f4(                          \
        aF[1], BS[0], z_, 0, 0, 0, 127, 0, 127);                                          \
    f32x4 t3 = __builtin_amdgcn_mfma_scale_f32_16x16x128_f8f6f4(                          \
        aF[1], BS[1], z_, 0, 0, 0, 127, 0, 127);                                          \
    __builtin_amdgcn_s_setprio(0);                                                        \
    acc[0][(NH)*2]     += t0 * svw[0];                                                    \
    acc[0][(NH)*2 + 1] += t1 * svw[0];                                                    \
    acc[1][(NH)*2]     += t2 * svw[1];                                                    \
    acc[1][(NH)*2 + 1] += t3 * svw[1];                                                    \
  }

  // prologue: stage kb=0 into buf 0
  STAGE_S(0, 0);
  STAGE_A(0, 0, 0); STAGE_A(1, 0, 0); STAGE_B(0, 0, 0); STAGE_B(1, 0, 0);
  asm volatile("s_waitcnt vmcnt(0)" ::: "memory");
  __builtin_amdgcn_s_barrier();
  __builtin_amdgcn_sched_barrier(0);

#pragma unroll 2
  for (int kb = 0; kb < NKB; ++kb) {
    const int cur = kb & 1;
    const int nxt = cur ^ 1;
    const int kbn = (kb + 1) & (NKB - 1);
    const int cb = cur * 16384;
    const float sw = wsp[kb];
    // ph0 (nt 0,1): all A frags + scales + B pair a; issue ALL 5 stages
    RD_A(0) RD_A(1) RD_SVW(0) RD_SVW(1) RD_B(0, bFa[0]) RD_B(1, bFa[1])
    STAGE_S(kbn, nxt);
    STAGE_A(0, kbn, nxt); STAGE_A(1, kbn, nxt);
    STAGE_B(0, kbn, nxt); STAGE_B(1, kbn, nxt);
    PH_WAIT MFMA_PH(0, bFa)
    // ph1 (nt 2,3)
    RD_B(2, bFb[0]) RD_B(3, bFb[1])
    PH_WAIT MFMA_PH(1, bFb)
    // single end sync per kb: drain own 5 stages, publish buffer nxt.
    // The drain stall is covered by the co-resident second block (4 w/SIMD).
    asm volatile("s_waitcnt vmcnt(0)" ::: "memory");
    __builtin_amdgcn_s_barrier();
    __builtin_amdgcn_sched_barrier(0);
  }

  // epilogue: resid += C.  row = m0+wm*32+mt*16+(j)+... col = n0+wn*64+nt*16+ln15
  const size_t rowstart = (size_t)(m0 + wm * 32 + g * 4) * HDIM + n0 + wn * 64 + ln15;
#pragma unroll
  for (int mt = 0; mt < 2; ++mt)
#pragma unroll
    for (int ntg = 0; ntg < 4; ++ntg)
#pragma unroll
      for (int j = 0; j < 4; ++j) {
        const size_t idx = rowstart + (size_t)(mt * 16 + j) * HDIM + ntg * 16;
        resid[idx] += acc[mt][ntg][j];
      }
#undef MFMA_PH
#undef PH_WAIT
#undef RD_B
#undef RD_SVW
#undef RD_A
#undef STAGE_A
#undef STAGE_B
#undef STAGE_S
}

extern "C" void kernel_launch(void* const* d_in, const int* in_sizes, int n_in,
                              void* d_out, int out_size, void* d_ws, size_t ws_size,
                              hipStream_t stream) {
  const float* x = (const float*)d_in[0];
  const float* norm_w = (const float*)d_in[1];
  const float* w = (const float*)d_in[2];
  const float* wscale = (const float*)d_in[3];
  float* out = (float*)d_out;
  char* ws = (char*)d_ws;

  size_t off = 0;
  unsigned char* w8 = (unsigned char*)(ws + off); off += 3ull * HDIM * HDIM;      // 48 MB
  float* resid = (float*)(ws + off);              off += (size_t)HDIM * HDIM * 4; // 64 MB
  unsigned char* qa = (unsigned char*)(ws + off); off += (size_t)HDIM * HDIM;     // 16 MB
  float* asc = (float*)(ws + off);                off += (size_t)NKB * HDIM * 4;  // 0.5 MB

  hipFuncSetAttribute((const void*)gemm256_kernel,
                      hipFuncAttributeMaxDynamicSharedMemorySize, 67584);

  const int n4 = 3 * HDIM * HDIM / 4;
  wquant_kernel<<<n4 / 256, 256, 0, stream>>>(w, w8, n4);
  norm_quant_kernel<0><<<HDIM, 256, 0, stream>>>(x, resid, norm_w, qa, asc, nullptr);
  for (int i = 0; i < 3; ++i) {
    gemm256_kernel<<<dim3(32, 32), 512, 67584, stream>>>(
        qa, asc, w8 + (size_t)i * HDIM * HDIM, wscale + i * NKB * NKB, resid);
    if (i < 2)
      norm_quant_kernel<1><<<HDIM, 256, 0, stream>>>(resid, nullptr, norm_w + (size_t)(i + 1) * HDIM, qa, asc, nullptr);
    else
      norm_quant_kernel<2><<<HDIM, 256, 0, stream>>>(resid, nullptr, norm_w + (size_t)3 * HDIM, nullptr, nullptr, out);
  }
}

// Round 11
// 783.340 us; speedup vs baseline: 1.5144x; 1.5144x over previous
//
#include <hip/hip_runtime.h>

typedef float f32x4 __attribute__((ext_vector_type(4)));
typedef int i32x4 __attribute__((ext_vector_type(4)));
typedef int i32x8 __attribute__((ext_vector_type(8)));

#define HDIM 4096
#define NKB 32  // 4096/128

// ---------------- K0: weight fp32 -> fp8 e4m3fn (RNE), row-major ----------------
__global__ __launch_bounds__(256) void wquant_kernel(const float* __restrict__ w,
                                                     unsigned char* __restrict__ w8,
                                                     int n4) {
  int i = blockIdx.x * 256 + threadIdx.x;
  if (i >= n4) return;
  const float4 v = ((const float4*)w)[i];
  int p = 0;
  p = __builtin_amdgcn_cvt_pk_fp8_f32(v.x, v.y, p, false);
  p = __builtin_amdgcn_cvt_pk_fp8_f32(v.z, v.w, p, true);
  ((int*)w8)[i] = p;
}

// ------------- K1/K3: (relu) + RMSNorm + group fp8 quant (row-major qa) -------------
template <int MODE>
__global__ __launch_bounds__(256) void norm_quant_kernel(
    const float* __restrict__ src, float* __restrict__ resid,
    const float* __restrict__ nw, unsigned char* __restrict__ qa,
    float* __restrict__ ascT, float* __restrict__ out) {
  const int row = blockIdx.x;
  const int tid = threadIdx.x;
  const float* srow = src + (size_t)row * HDIM;
  float4 v[4];
  float ss = 0.f;
#pragma unroll
  for (int c = 0; c < 4; ++c) {
    float4 t = ((const float4*)srow)[c * 256 + tid];
    if (MODE == 0) {
      t.x = fmaxf(t.x, 0.f); t.y = fmaxf(t.y, 0.f);
      t.z = fmaxf(t.z, 0.f); t.w = fmaxf(t.w, 0.f);
      ((float4*)(resid + (size_t)row * HDIM))[c * 256 + tid] = t;
    }
    v[c] = t;
    ss += t.x * t.x + t.y * t.y + t.z * t.z + t.w * t.w;
  }
#pragma unroll
  for (int m = 32; m >= 1; m >>= 1) ss += __shfl_xor(ss, m);
  __shared__ float red[4];
  if ((tid & 63) == 0) red[tid >> 6] = ss;
  __syncthreads();
  const float tot = red[0] + red[1] + red[2] + red[3];
  const float rstd = rsqrtf(tot * (1.f / (float)HDIM) + 1e-6f);
#pragma unroll
  for (int c = 0; c < 4; ++c) {
    float4 wv = ((const float4*)nw)[c * 256 + tid];
    float4 y;
    y.x = v[c].x * rstd * wv.x;
    y.y = v[c].y * rstd * wv.y;
    y.z = v[c].z * rstd * wv.z;
    y.w = v[c].w * rstd * wv.w;
    if (MODE == 2) {
      ((float4*)(out + (size_t)row * HDIM))[c * 256 + tid] = y;
    } else {
      float amax = fmaxf(fmaxf(fabsf(y.x), fabsf(y.y)), fmaxf(fabsf(y.z), fabsf(y.w)));
#pragma unroll
      for (int m = 16; m >= 1; m >>= 1) amax = fmaxf(amax, __shfl_xor(amax, m));
      const float scale = fmaxf(amax / 448.f, 1e-10f);
      const float qinv = __builtin_amdgcn_rcpf(scale);
      float qx = fminf(fmaxf(y.x * qinv, -448.f), 448.f);
      float qy = fminf(fmaxf(y.y * qinv, -448.f), 448.f);
      float qz = fminf(fmaxf(y.z * qinv, -448.f), 448.f);
      float qw = fminf(fmaxf(y.w * qinv, -448.f), 448.f);
      int p = 0;
      p = __builtin_amdgcn_cvt_pk_fp8_f32(qx, qy, p, false);
      p = __builtin_amdgcn_cvt_pk_fp8_f32(qz, qw, p, true);
      const int off = (c * 256 + tid) << 2;
      *(int*)(qa + (size_t)row * HDIM + off) = p;
      if ((tid & 31) == 0) ascT[(c * 8 + (tid >> 5)) * HDIM + row] = scale;
    }
  }
}

// ---------------- K2: 128x128 block-scaled fp8 GEMM via MX-rate MFMA ---------
// Two-blocks-per-CU retile of R8: 128x128 tile, 256 threads (4 waves = 2wm x
// 2wn, per-wave 64x64 out, acc[4][4]=64 regs in AGPR), __launch_bounds__(256,2)
// -> 256 unified regs/wave (R8's proven no-spill regime). LDS = 2 x (16K A +
// 16K B + 1K S) = 66K -> TWO independent blocks co-resident per CU (132K <=
// 160K): when one block sits in its vmcnt+barrier drain, the other's waves on
// the same SIMDs keep issuing — the cover R8's single barrier group lacked.
// Schedule = R8's skeleton halved, invariants verbatim: 4 thin phases/kb
// (4 MFMA + immediate fold, per-phase PH_WAIT), stages front-loaded
// (S,A0-A2 @ph0; A3,B0,B2 @ph1; B1,B3 @ph2);
//   mid: vmcnt(7) (= prev{B1,B3} + this 7 issued; drains exactly the bFb
//        chunks) + barrier, before ph2 reads B chunks 1/3;
//   end: vmcnt(2) (leaves B1,B3 in flight) + barrier.
__global__ __launch_bounds__(256, 2) void gemm256_kernel(
    const unsigned char* __restrict__ qa, const float* __restrict__ ascT,
    const unsigned char* __restrict__ w8, const float* __restrict__ wsc,
    float* __restrict__ resid) {
  extern __shared__ char smem[];
  char* ldsA = smem;            // 2 x 16384
  char* ldsB = smem + 32768;    // 2 x 16384
  char* ldsS = smem + 65536;    // 2 x 1024 (512B used)

  const int tid = threadIdx.x;
  const int lane = tid & 63;
  const int wid = tid >> 6;  // 0..3
  const int wm = wid >> 1;   // 0..1 (64-row group)
  const int wn = wid & 1;    // 0..1 (64-col group)

  // XCD-aware bijective swizzle of the 32x32 grid (8 XCDs x 128 blocks);
  // within a chunk n0 varies fastest -> blocks share m0 (A panel hot in L2).
  const int bflat = blockIdx.y * 32 + blockIdx.x;
  const int bswz = (bflat & 7) * 128 + (bflat >> 3);
  const int m0 = (bswz >> 5) << 7;
  const int n0 = (bswz & 31) << 7;

  const int ln15 = lane & 15;
  const int g = lane >> 4;

  // staging source offsets (row-major qa/w8): chunk CH = 4KB = 2 tiles;
  // thread t writes chunk unit t: tile (t>>7)&1, half (t>>6)&1, lane t&63.
  // Source row = CH*32 + tile*16 + (t&15), k = ((t>>4)&3)*32 + half*16.
  int ofs[4];
  {
    const int rowp = ((tid >> 7) & 1) * 16 + (tid & 15);
    const int kp = ((tid >> 4) & 3) * 32 + ((tid >> 6) & 1) * 16;
#pragma unroll
    for (int ch = 0; ch < 4; ++ch) ofs[ch] = (ch * 32 + rowp) * HDIM + kp;
  }
  const unsigned char* gA = qa + (size_t)m0 * HDIM;
  const unsigned char* gB = w8 + (size_t)n0 * HDIM;
  const float* sS = ascT + m0 + tid * 4;  // threads 0..31 cover 128 rows

  const float* wsp = wsc + (n0 >> 7) * NKB;  // one 128-col scale block/tile

  const int abase = wm * 8192 + lane * 16;   // wm covers tiles wm*4 + mt
  const int bbase = wn * 8192 + lane * 16;   // wn covers tiles wn*4 + nt
  const int svb = wm * 256 + g * 16;

  f32x4 acc[4][4];
#pragma unroll
  for (int i = 0; i < 4; ++i)
#pragma unroll
    for (int j = 0; j < 4; ++j) acc[i][j] = (f32x4){0.f, 0.f, 0.f, 0.f};

  i32x8 aF[4];         // [mt] 32B fragment
  i32x8 bFa[2];        // nt pair 0,1 (chunks 0/2)
  i32x8 bFb[2];        // nt pair 2,3 (chunks 1/3)
  f32x4 svw[4];        // sa*sw per mt

#define STAGE_A(CH, KB, BUF)                                                              \
  __builtin_amdgcn_global_load_lds(                                                       \
      (const __attribute__((address_space(1))) void*)(gA + ofs[CH] + (KB)*128),           \
      (__attribute__((address_space(3))) void*)(ldsA + (BUF)*16384 + (CH)*4096 + tid*16), \
      16, 0, 0)
#define STAGE_B(CH, KB, BUF)                                                              \
  __builtin_amdgcn_global_load_lds(                                                       \
      (const __attribute__((address_space(1))) void*)(gB + ofs[CH] + (KB)*128),           \
      (__attribute__((address_space(3))) void*)(ldsB + (BUF)*16384 + (CH)*4096 + tid*16), \
      16, 0, 0)
#define STAGE_S(KB, BUF)                                                                  \
  if (tid < 32)                                                                           \
  __builtin_amdgcn_global_load_lds(                                                       \
      (const __attribute__((address_space(1))) void*)(sS + (size_t)(KB)*HDIM),            \
      (__attribute__((address_space(3))) void*)(ldsS + (BUF)*1024 + tid*16), 16, 0, 0)

#define RD_A(MT)                                                                          \
  {                                                                                       \
    const char* pA_ = ldsA + cb + abase + (MT)*2048;                                      \
    i32x4 lo_ = *(const i32x4*)pA_;                                                       \
    i32x4 hi_ = *(const i32x4*)(pA_ + 1024);                                              \
    aF[MT] = __builtin_shufflevector(lo_, hi_, 0, 1, 2, 3, 4, 5, 6, 7);                   \
  }
#define RD_SVW(MT) svw[MT] = *(const f32x4*)(ldsS + cur * 1024 + svb + (MT)*64) * sw;
#define RD_B(NT, DST)                                                                     \
  {                                                                                       \
    const char* pB_ = ldsB + cb + bbase + (NT)*2048;                                      \
    i32x4 lo_ = *(const i32x4*)pB_;                                                       \
    i32x4 hi_ = *(const i32x4*)(pB_ + 1024);                                              \
    DST = __builtin_shufflevector(lo_, hi_, 0, 1, 2, 3, 4, 5, 6, 7);                      \
  }

// wave-local phase ordering: wait own ds_reads, pin program order. No barrier.
#define PH_WAIT                                                                           \
  asm volatile("s_waitcnt lgkmcnt(0)" ::: "memory");                                      \
  __builtin_amdgcn_sched_barrier(0);

#define MFMA_PH(MTA, MTB, NT0, BS)                                                        \
  __builtin_amdgcn_s_setprio(1);                                                          \
  {                                                                                       \
    const f32x4 z_ = (f32x4){0.f, 0.f, 0.f, 0.f};                                         \
    f32x4 t0 = __builtin_amdgcn_mfma_scale_f32_16x16x128_f8f6f4(                          \
        aF[MTA], BS[0], z_, 0, 0, 0, 127, 0, 127);                                        \
    f32x4 t1 = __builtin_amdgcn_mfma_scale_f32_16x16x128_f8f6f4(                          \
        aF[MTA], BS[1], z_, 0, 0, 0, 127, 0, 127);                                        \
    f32x4 t2 = __builtin_amdgcn_mfma_scale_f32_16x16x128_f8f6f4(                          \
        aF[MTB], BS[0], z_, 0, 0, 0, 127, 0, 127);                                        \
    f32x4 t3 = __builtin_amdgcn_mfma_scale_f32_16x16x128_f8f6f4(                          \
        aF[MTB], BS[1], z_, 0, 0, 0, 127, 0, 127);                                        \
    __builtin_amdgcn_s_setprio(0);                                                        \
    acc[MTA][(NT0)]     += t0 * svw[MTA];                                                 \
    acc[MTA][(NT0) + 1] += t1 * svw[MTA];                                                 \
    acc[MTB][(NT0)]     += t2 * svw[MTB];                                                 \
    acc[MTB][(NT0) + 1] += t3 * svw[MTB];                                                 \
  }

  // prologue: stage kb=0 into buf 0 (steady-state issue order)
  STAGE_S(0, 0);
  STAGE_A(0, 0, 0); STAGE_A(1, 0, 0); STAGE_A(2, 0, 0); STAGE_A(3, 0, 0);
  STAGE_B(0, 0, 0); STAGE_B(2, 0, 0); STAGE_B(1, 0, 0); STAGE_B(3, 0, 0);
  asm volatile("s_waitcnt vmcnt(2)" ::: "memory");
  __builtin_amdgcn_s_barrier();
  __builtin_amdgcn_sched_barrier(0);

#pragma unroll 2
  for (int kb = 0; kb < NKB; ++kb) {
    const int cur = kb & 1;
    const int nxt = cur ^ 1;
    const int kbn = (kb + 1) & (NKB - 1);
    const int cb = cur * 16384;
    const float sw = wsp[kb];
    // ph0 (mt 0,1 x nt 0,1): all A frags + scales + bFa (chunks 0/2)
    RD_A(0) RD_A(1) RD_A(2) RD_A(3)
    RD_SVW(0) RD_SVW(1) RD_SVW(2) RD_SVW(3)
    RD_B(0, bFa[0]) RD_B(1, bFa[1])
    STAGE_S(kbn, nxt);
    STAGE_A(0, kbn, nxt); STAGE_A(1, kbn, nxt); STAGE_A(2, kbn, nxt);
    PH_WAIT MFMA_PH(0, 1, 0, bFa)
    // ph1 (mt 2,3 x nt 0,1)
    STAGE_A(3, kbn, nxt); STAGE_B(0, kbn, nxt); STAGE_B(2, kbn, nxt);
    PH_WAIT MFMA_PH(2, 3, 0, bFa)
    // ---- mid sync: outstanding = prev{B1,B3} + this{S,A0..A3,B0,B2} = 9;
    //      drain only prev B1,B3 -> vmcnt(7)
    asm volatile("s_waitcnt vmcnt(7)" ::: "memory");
    __builtin_amdgcn_s_barrier();
    __builtin_amdgcn_sched_barrier(0);
    // ph2 (mt 2,3 x nt 2,3): bFb (chunks 1/3), safe after mid sync
    RD_B(2, bFb[0]) RD_B(3, bFb[1])
    STAGE_B(1, kbn, nxt); STAGE_B(3, kbn, nxt);
    PH_WAIT MFMA_PH(2, 3, 2, bFb)
    // ph3 (mt 0,1 x nt 2,3)
    PH_WAIT MFMA_PH(0, 1, 2, bFb)
    // ---- end sync: drain this kb's {S,A0..A3,B0,B2}; leave {B1,B3} in flight
    asm volatile("s_waitcnt vmcnt(2)" ::: "memory");
    __builtin_amdgcn_s_barrier();
    __builtin_amdgcn_sched_barrier(0);
  }

  // epilogue: resid += C. row = m0+wm*64+mt*16+g*4+j, col = n0+wn*64+nt*16+ln15
  const size_t rowstart = (size_t)(m0 + wm * 64 + g * 4) * HDIM + n0 + wn * 64 + ln15;
#pragma unroll
  for (int mt = 0; mt < 4; ++mt)
#pragma unroll
    for (int nt = 0; nt < 4; ++nt)
#pragma unroll
      for (int j = 0; j < 4; ++j) {
        const size_t idx = rowstart + (size_t)(mt * 16 + j) * HDIM + nt * 16;
        resid[idx] += acc[mt][nt][j];
      }
#undef MFMA_PH
#undef PH_WAIT
#undef RD_B
#undef RD_SVW
#undef RD_A
#undef STAGE_A
#undef STAGE_B
#undef STAGE_S
}

extern "C" void kernel_launch(void* const* d_in, const int* in_sizes, int n_in,
                              void* d_out, int out_size, void* d_ws, size_t ws_size,
                              hipStream_t stream) {
  const float* x = (const float*)d_in[0];
  const float* norm_w = (const float*)d_in[1];
  const float* w = (const float*)d_in[2];
  const float* wscale = (const float*)d_in[3];
  float* out = (float*)d_out;
  char* ws = (char*)d_ws;

  size_t off = 0;
  unsigned char* w8 = (unsigned char*)(ws + off); off += 3ull * HDIM * HDIM;      // 48 MB
  float* resid = (float*)(ws + off);              off += (size_t)HDIM * HDIM * 4; // 64 MB
  unsigned char* qa = (unsigned char*)(ws + off); off += (size_t)HDIM * HDIM;     // 16 MB
  float* asc = (float*)(ws + off);                off += (size_t)NKB * HDIM * 4;  // 0.5 MB

  hipFuncSetAttribute((const void*)gemm256_kernel,
                      hipFuncAttributeMaxDynamicSharedMemorySize, 67584);

  const int n4 = 3 * HDIM * HDIM / 4;
  wquant_kernel<<<n4 / 256, 256, 0, stream>>>(w, w8, n4);
  norm_quant_kernel<0><<<HDIM, 256, 0, stream>>>(x, resid, norm_w, qa, asc, nullptr);
  for (int i = 0; i < 3; ++i) {
    gemm256_kernel<<<dim3(32, 32), 256, 67584, stream>>>(
        qa, asc, w8 + (size_t)i * HDIM * HDIM, wscale + i * NKB * NKB, resid);
    if (i < 2)
      norm_quant_kernel<1><<<HDIM, 256, 0, stream>>>(resid, nullptr, norm_w + (size_t)(i + 1) * HDIM, qa, asc, nullptr);
    else
      norm_quant_kernel<2><<<HDIM, 256, 0, stream>>>(resid, nullptr, norm_w + (size_t)3 * HDIM, nullptr, nullptr, out);
  }
}

// Round 12
// 398.258 us; speedup vs baseline: 2.9788x; 1.9669x over previous
//
#include <hip/hip_runtime.h>

typedef float f32x4 __attribute__((ext_vector_type(4)));
typedef int i32x4 __attribute__((ext_vector_type(4)));
typedef int i32x8 __attribute__((ext_vector_type(8)));

#define HDIM 4096
#define NKB 32  // 4096/128

// ---------------- K0: weight fp32 -> fp8 e4m3fn (RNE), row-major ----------------
__global__ __launch_bounds__(256) void wquant_kernel(const float* __restrict__ w,
                                                     unsigned char* __restrict__ w8,
                                                     int n4) {
  int i = blockIdx.x * 256 + threadIdx.x;
  if (i >= n4) return;
  const float4 v = ((const float4*)w)[i];
  int p = 0;
  p = __builtin_amdgcn_cvt_pk_fp8_f32(v.x, v.y, p, false);
  p = __builtin_amdgcn_cvt_pk_fp8_f32(v.z, v.w, p, true);
  ((int*)w8)[i] = p;
}

// ------------- K1/K3: (relu) + RMSNorm + group fp8 quant (row-major qa) -------------
template <int MODE>
__global__ __launch_bounds__(256) void norm_quant_kernel(
    const float* __restrict__ src, float* __restrict__ resid,
    const float* __restrict__ nw, unsigned char* __restrict__ qa,
    float* __restrict__ ascT, float* __restrict__ out) {
  const int row = blockIdx.x;
  const int tid = threadIdx.x;
  const float* srow = src + (size_t)row * HDIM;
  float4 v[4];
  float ss = 0.f;
#pragma unroll
  for (int c = 0; c < 4; ++c) {
    float4 t = ((const float4*)srow)[c * 256 + tid];
    if (MODE == 0) {
      t.x = fmaxf(t.x, 0.f); t.y = fmaxf(t.y, 0.f);
      t.z = fmaxf(t.z, 0.f); t.w = fmaxf(t.w, 0.f);
      ((float4*)(resid + (size_t)row * HDIM))[c * 256 + tid] = t;
    }
    v[c] = t;
    ss += t.x * t.x + t.y * t.y + t.z * t.z + t.w * t.w;
  }
#pragma unroll
  for (int m = 32; m >= 1; m >>= 1) ss += __shfl_xor(ss, m);
  __shared__ float red[4];
  if ((tid & 63) == 0) red[tid >> 6] = ss;
  __syncthreads();
  const float tot = red[0] + red[1] + red[2] + red[3];
  const float rstd = rsqrtf(tot * (1.f / (float)HDIM) + 1e-6f);
#pragma unroll
  for (int c = 0; c < 4; ++c) {
    float4 wv = ((const float4*)nw)[c * 256 + tid];
    float4 y;
    y.x = v[c].x * rstd * wv.x;
    y.y = v[c].y * rstd * wv.y;
    y.z = v[c].z * rstd * wv.z;
    y.w = v[c].w * rstd * wv.w;
    if (MODE == 2) {
      ((float4*)(out + (size_t)row * HDIM))[c * 256 + tid] = y;
    } else {
      float amax = fmaxf(fmaxf(fabsf(y.x), fabsf(y.y)), fmaxf(fabsf(y.z), fabsf(y.w)));
#pragma unroll
      for (int m = 16; m >= 1; m >>= 1) amax = fmaxf(amax, __shfl_xor(amax, m));
      const float scale = fmaxf(amax / 448.f, 1e-10f);
      const float qinv = __builtin_amdgcn_rcpf(scale);
      float qx = fminf(fmaxf(y.x * qinv, -448.f), 448.f);
      float qy = fminf(fmaxf(y.y * qinv, -448.f), 448.f);
      float qz = fminf(fmaxf(y.z * qinv, -448.f), 448.f);
      float qw = fminf(fmaxf(y.w * qinv, -448.f), 448.f);
      int p = 0;
      p = __builtin_amdgcn_cvt_pk_fp8_f32(qx, qy, p, false);
      p = __builtin_amdgcn_cvt_pk_fp8_f32(qz, qw, p, true);
      const int off = (c * 256 + tid) << 2;
      *(int*)(qa + (size_t)row * HDIM + off) = p;
      if ((tid & 31) == 0) ascT[(c * 8 + (tid >> 5)) * HDIM + row] = scale;
    }
  }
}

// ---------------- K2: 256x256 block-scaled fp8 GEMM via MX-rate MFMA ---------
// R8 final form (session best, 399.3 us): 8 thin phases/kb (4 MFMA +
// immediate fold), per-phase PH_WAIT (lgkmcnt(0)+sched_barrier — R5 proved
// removing them hurts), TWO barriers/kb with counted vmcnt (R9 proved
// draining to 0 hurts). Staging issue order per kb: S,A0 (ph0) A1,A2 (ph1)
// A3,B0,B2 (ph2) B1 (ph4) B3 (ph6).
//   mid: vmcnt(7) (outstanding = prev{B1,B3} + this{S,A0..A3,B0,B2}=9; drain
//        only prev B1,B3) + barrier, before ph4+ reads B chunks 1/3;
//   end: vmcnt(2) (drain this kb's S..B2; leave B1,B3 in flight) + barrier.
// Structural notes from the session: occupancy is register-pinned at
// 2 waves/SIMD (acc = 128 AGPR -> 256 unified regs/wave; R7/R10 spilled,
// R11 gained no waves and thrashed L2); A must stay LDS-staged (R6: global
// A loads poison the vmcnt FIFO); cross-barrier register state = aF/bFa/
// bFb/svw only (R2: MFMA-result liveness across barriers spills).
__global__ __launch_bounds__(512, 2) void gemm256_kernel(
    const unsigned char* __restrict__ qa, const float* __restrict__ ascT,
    const unsigned char* __restrict__ w8, const float* __restrict__ wsc,
    float* __restrict__ resid) {
  extern __shared__ char smem[];
  char* ldsA = smem;            // 2 x 32768
  char* ldsB = smem + 65536;    // 2 x 32768
  char* ldsS = smem + 131072;   // 2 x 1024

  const int tid = threadIdx.x;
  const int lane = tid & 63;
  const int wid = tid >> 6;
  const int wm = wid >> 1;   // 0..3
  const int wn = wid & 1;    // 0..1

  // XCD-aware bijective swizzle of the 16x16 grid (8 XCDs x 32 blocks)
  const int bflat = blockIdx.y * 16 + blockIdx.x;
  const int bswz = (bflat & 7) * 32 + (bflat >> 3);
  const int m0 = (bswz >> 4) << 8;
  const int n0 = (bswz & 15) << 8;

  const int ln15 = lane & 15;
  const int g = lane >> 4;

  // staging source offsets (row-major qa/w8): chunk CH = 8KB; thread t writes
  // LDS bytes [CH*8192 + t*16, +16) = tile (CH*4 + (t>>7)), half ((t>>6)&1),
  // lane (t&63). Source = row (tile*16 + (t&15)), k = ((t>>4)&3)*32 + half*16.
  int ofs[4];
  {
    const int rowp = ((tid >> 7) & 3) * 16 + (tid & 15);
    const int kp = ((tid >> 4) & 3) * 32 + ((tid >> 6) & 1) * 16;
#pragma unroll
    for (int ch = 0; ch < 4; ++ch) ofs[ch] = (ch * 64 + rowp) * HDIM + kp;
  }
  const unsigned char* gA = qa + (size_t)m0 * HDIM;
  const unsigned char* gB = w8 + (size_t)n0 * HDIM;
  const float* sS = ascT + m0 + lane * 4;

  const int nb = __builtin_amdgcn_readfirstlane((n0 >> 7) + wn);
  const float* wsp = wsc + nb * NKB;

  const int abase = wm * 8192 + lane * 16;
  const int bbase = wn * 16384 + lane * 16;
  const int svb = wm * 256 + g * 16;

  f32x4 acc[4][8];
#pragma unroll
  for (int i = 0; i < 4; ++i)
#pragma unroll
    for (int j = 0; j < 8; ++j) acc[i][j] = (f32x4){0.f, 0.f, 0.f, 0.f};

  i32x8 aF[4];         // [mt] 32B fragment
  i32x8 bFa[2];        // set a: [nt]
  i32x8 bFb[2];        // set b
  f32x4 svw[4];        // sa*sw

#define STAGE_A(CH, KB, BUF)                                                              \
  __builtin_amdgcn_global_load_lds(                                                       \
      (const __attribute__((address_space(1))) void*)(gA + ofs[CH] + (KB)*128),           \
      (__attribute__((address_space(3))) void*)(ldsA + (BUF)*32768 + (CH)*8192 + tid*16), \
      16, 0, 0)
#define STAGE_B(CH, KB, BUF)                                                              \
  __builtin_amdgcn_global_load_lds(                                                       \
      (const __attribute__((address_space(1))) void*)(gB + ofs[CH] + (KB)*128),           \
      (__attribute__((address_space(3))) void*)(ldsB + (BUF)*32768 + (CH)*8192 + tid*16), \
      16, 0, 0)
#define STAGE_S(KB, BUF)                                                                  \
  __builtin_amdgcn_global_load_lds(                                                       \
      (const __attribute__((address_space(1))) void*)(sS + (size_t)(KB)*HDIM),            \
      (__attribute__((address_space(3))) void*)(ldsS + (BUF)*1024 + lane*16), 16, 0, 0)

#define RD_A(MT)                                                                          \
  {                                                                                       \
    const char* pA_ = ldsA + cb + abase + (MT)*2048;                                      \
    i32x4 lo_ = *(const i32x4*)pA_;                                                       \
    i32x4 hi_ = *(const i32x4*)(pA_ + 1024);                                              \
    aF[MT] = __builtin_shufflevector(lo_, hi_, 0, 1, 2, 3, 4, 5, 6, 7);                   \
  }
#define RD_SVW(MT) svw[MT] = *(const f32x4*)(ldsS + cur * 1024 + svb + (MT)*64) * sw;
#define RD_BS(BS, NH)                                                                     \
  {                                                                                       \
    const char* p0_ = ldsB + cb + bbase + ((NH)*2) * 2048;                                \
    i32x4 l0_ = *(const i32x4*)p0_;                                                       \
    i32x4 h0_ = *(const i32x4*)(p0_ + 1024);                                              \
    BS[0] = __builtin_shufflevector(l0_, h0_, 0, 1, 2, 3, 4, 5, 6, 7);                    \
    const char* p1_ = p0_ + 2048;                                                         \
    i32x4 l1_ = *(const i32x4*)p1_;                                                       \
    i32x4 h1_ = *(const i32x4*)(p1_ + 1024);                                              \
    BS[1] = __builtin_shufflevector(l1_, h1_, 0, 1, 2, 3, 4, 5, 6, 7);                    \
  }

// wave-local phase ordering: wait own ds_reads, pin program order. No barrier.
#define PH_WAIT                                                                           \
  asm volatile("s_waitcnt lgkmcnt(0)" ::: "memory");                                      \
  __builtin_amdgcn_sched_barrier(0);

#define MFMA_PH(MTA, MTB, NH, BS)                                                         \
  __builtin_amdgcn_s_setprio(1);                                                          \
  {                                                                                       \
    const f32x4 z_ = (f32x4){0.f, 0.f, 0.f, 0.f};                                         \
    f32x4 t0 = __builtin_amdgcn_mfma_scale_f32_16x16x128_f8f6f4(                          \
        aF[MTA], BS[0], z_, 0, 0, 0, 127, 0, 127);                                        \
    f32x4 t1 = __builtin_amdgcn_mfma_scale_f32_16x16x128_f8f6f4(                          \
        aF[MTA], BS[1], z_, 0, 0, 0, 127, 0, 127);                                        \
    f32x4 t2 = __builtin_amdgcn_mfma_scale_f32_16x16x128_f8f6f4(                          \
        aF[MTB], BS[0], z_, 0, 0, 0, 127, 0, 127);                                        \
    f32x4 t3 = __builtin_amdgcn_mfma_scale_f32_16x16x128_f8f6f4(                          \
        aF[MTB], BS[1], z_, 0, 0, 0, 127, 0, 127);                                        \
    __builtin_amdgcn_s_setprio(0);                                                        \
    acc[MTA][(NH)*2]     += t0 * svw[MTA];                                                \
    acc[MTA][(NH)*2 + 1] += t1 * svw[MTA];                                                \
    acc[MTB][(NH)*2]     += t2 * svw[MTB];                                                \
    acc[MTB][(NH)*2 + 1] += t3 * svw[MTB];                                                \
  }

  // prologue: stage kb=0 into buf 0 (order = steady-state issue order)
  STAGE_S(0, 0); STAGE_A(0, 0, 0); STAGE_A(1, 0, 0); STAGE_A(2, 0, 0); STAGE_A(3, 0, 0);
  STAGE_B(0, 0, 0); STAGE_B(2, 0, 0); STAGE_B(1, 0, 0); STAGE_B(3, 0, 0);
  asm volatile("s_waitcnt vmcnt(2)" ::: "memory");
  __builtin_amdgcn_s_barrier();
  __builtin_amdgcn_sched_barrier(0);

#pragma unroll 2
  for (int kb = 0; kb < NKB; ++kb) {
    const int cur = kb & 1;
    const int nxt = cur ^ 1;
    const int kbn = (kb + 1) & (NKB - 1);
    const int cb = cur * 32768;
    const float sw = wsp[kb];
    // ph0 (M:0,1 N0, set a)
    RD_A(0) RD_A(1) RD_SVW(0) RD_SVW(1) RD_BS(bFa, 0)
    STAGE_S(kbn, nxt); STAGE_A(0, kbn, nxt);
    PH_WAIT MFMA_PH(0, 1, 0, bFa)
    // ph1 (M:2,3 N0, set a)
    RD_A(2) RD_A(3) RD_SVW(2) RD_SVW(3)
    STAGE_A(1, kbn, nxt); STAGE_A(2, kbn, nxt);
    PH_WAIT MFMA_PH(2, 3, 0, bFa)
    // ph2 (M:2,3 N1, set b) — B2 issued here: 5 phases of headroom
    RD_BS(bFb, 1)
    STAGE_A(3, kbn, nxt); STAGE_B(0, kbn, nxt); STAGE_B(2, kbn, nxt);
    PH_WAIT MFMA_PH(2, 3, 1, bFb)
    // ph3 (M:0,1 N1, set b)
    PH_WAIT MFMA_PH(0, 1, 1, bFb)
    // ---- mid sync: outstanding = prev{B1,B3} + this{S,A0..A3,B0,B2} = 9;
    //      drain only prev B1,B3 -> vmcnt(7)
    asm volatile("s_waitcnt vmcnt(7)" ::: "memory");
    __builtin_amdgcn_s_barrier();
    __builtin_amdgcn_sched_barrier(0);
    // ph4 (M:0,1 N2, set a) — reads B chunks 1/3, safe after mid sync
    RD_BS(bFa, 2)
    STAGE_B(1, kbn, nxt);
    PH_WAIT MFMA_PH(0, 1, 2, bFa)
    // ph5 (M:2,3 N2, set a)
    PH_WAIT MFMA_PH(2, 3, 2, bFa)
    // ph6 (M:2,3 N3, set b)
    RD_BS(bFb, 3)
    STAGE_B(3, kbn, nxt);
    PH_WAIT MFMA_PH(2, 3, 3, bFb)
    // ph7 (M:0,1 N3, set b)
    PH_WAIT MFMA_PH(0, 1, 3, bFb)
    // ---- end sync: drain this kb's {S,A0..A3,B0,B2}; leave {B1,B3} in flight
    asm volatile("s_waitcnt vmcnt(2)" ::: "memory");
    __builtin_amdgcn_s_barrier();
    __builtin_amdgcn_sched_barrier(0);
  }

  // epilogue: resid += C
  const size_t rowstart = (size_t)(m0 + wm * 64 + g * 4) * HDIM + n0 + wn * 128 + ln15;
#pragma unroll
  for (int mt = 0; mt < 4; ++mt)
#pragma unroll
    for (int ntg = 0; ntg < 8; ++ntg)
#pragma unroll
      for (int j = 0; j < 4; ++j) {
        const size_t idx = rowstart + (size_t)(mt * 16 + j) * HDIM + ntg * 16;
        resid[idx] += acc[mt][ntg][j];
      }
#undef MFMA_PH
#undef PH_WAIT
#undef RD_BS
#undef RD_SVW
#undef RD_A
#undef STAGE_A
#undef STAGE_B
#undef STAGE_S
}

extern "C" void kernel_launch(void* const* d_in, const int* in_sizes, int n_in,
                              void* d_out, int out_size, void* d_ws, size_t ws_size,
                              hipStream_t stream) {
  const float* x = (const float*)d_in[0];
  const float* norm_w = (const float*)d_in[1];
  const float* w = (const float*)d_in[2];
  const float* wscale = (const float*)d_in[3];
  float* out = (float*)d_out;
  char* ws = (char*)d_ws;

  size_t off = 0;
  unsigned char* w8 = (unsigned char*)(ws + off); off += 3ull * HDIM * HDIM;      // 48 MB
  float* resid = (float*)(ws + off);              off += (size_t)HDIM * HDIM * 4; // 64 MB
  unsigned char* qa = (unsigned char*)(ws + off); off += (size_t)HDIM * HDIM;     // 16 MB
  float* asc = (float*)(ws + off);                off += (size_t)NKB * HDIM * 4;  // 0.5 MB

  hipFuncSetAttribute((const void*)gemm256_kernel,
                      hipFuncAttributeMaxDynamicSharedMemorySize, 133120);

  const int n4 = 3 * HDIM * HDIM / 4;
  wquant_kernel<<<n4 / 256, 256, 0, stream>>>(w, w8, n4);
  norm_quant_kernel<0><<<HDIM, 256, 0, stream>>>(x, resid, norm_w, qa, asc, nullptr);
  for (int i = 0; i < 3; ++i) {
    gemm256_kernel<<<dim3(16, 16), 512, 133120, stream>>>(
        qa, asc, w8 + (size_t)i * HDIM * HDIM, wscale + i * NKB * NKB, resid);
    if (i < 2)
      norm_quant_kernel<1><<<HDIM, 256, 0, stream>>>(resid, nullptr, norm_w + (size_t)(i + 1) * HDIM, qa, asc, nullptr);
    else
      norm_quant_kernel<2><<<HDIM, 256, 0, stream>>>(resid, nullptr, norm_w + (size_t)3 * HDIM, nullptr, nullptr, out);
  }
}